// Round 6
// baseline (1160.339 us; speedup 1.0000x reference)
//
#include <hip/hip_runtime.h>

#define HN 192
#define TT 2048
#define NCLS 12
#define ROWB 768
#define SEGB 288
// LDS layout (bytes)
#define L0_PAD    147456           // zero row (768B) right after W0
#define LDS_LIST0 148224           // 2 bufs x 3 segs x 288B = 1728
#define LDS_CNT   149952           // 2 x 16B (int4 of per-wave counts)
#define LDS_S0    149984           // 2 x 768B s0 double buffer
#define LDS_LIST1 151520           // wave3-private list, 200*4B
#define LDS_FEAT  152320           // 768B
#define LDS_TOTAL 153088

// ws layout (floats): [w0 rows 0..191][zero row][w1 rows 0..191][256f pad]
__global__ void snn_pack_k(const float* __restrict__ Wc, float* __restrict__ ws) {
  int idx = blockIdx.x * 256 + threadIdx.x;
  if (idx < HN * HN) {                       // layer 0: Wc[0][i][j] -> ws[j*192+i]
    int i = idx / HN, j = idx % HN;
    ws[j * HN + i] = Wc[idx];
  } else if (idx < 2 * HN * HN) {            // layer 1 -> rows 193..384
    int r = idx - HN * HN;
    int i = r / HN, j = r % HN;
    ws[(193 + j) * HN + i] = Wc[idx];
  } else {
    int r = idx - 2 * HN * HN;
    if (r < HN) ws[192 * HN + r] = 0.0f;     // zero row
    if (r < 256) ws[385 * HN + r] = 0.0f;    // tail pad
  }
}

struct F3 { float x, y, z; };

__device__ __forceinline__ int lanecnt_lt(unsigned long long m) {
  return __builtin_amdgcn_mbcnt_hi((unsigned)(m >> 32),
           __builtin_amdgcn_mbcnt_lo((unsigned)m, 0u));
}

#define READC(da, db, base, c) do { \
  da = *(const int4*)((base) + (c) * 32); \
  db = *(const int4*)((base) + (c) * 32 + 16); } while (0)

#define ISS8L0(p, ca, cb) do { \
  p##0 = *(const float*)(ldsb + (unsigned)(ca).x + nn4); \
  p##1 = *(const float*)(ldsb + (unsigned)(ca).y + nn4); \
  p##2 = *(const float*)(ldsb + (unsigned)(ca).z + nn4); \
  p##3 = *(const float*)(ldsb + (unsigned)(ca).w + nn4); \
  p##4 = *(const float*)(ldsb + (unsigned)(cb).x + nn4); \
  p##5 = *(const float*)(ldsb + (unsigned)(cb).y + nn4); \
  p##6 = *(const float*)(ldsb + (unsigned)(cb).z + nn4); \
  p##7 = *(const float*)(ldsb + (unsigned)(cb).w + nn4); } while (0)

#define CONS8F(acc, p) acc += ((((p##0) + (p##1)) + ((p##2) + (p##3))) + \
                               (((p##4) + (p##5)) + ((p##6) + (p##7))))

#define ISS8W1(p, ca, cb) do { \
  p##0 = *(const F3*)(w1zb + (unsigned)(ca).x + ln12); \
  p##1 = *(const F3*)(w1zb + (unsigned)(ca).y + ln12); \
  p##2 = *(const F3*)(w1zb + (unsigned)(ca).z + ln12); \
  p##3 = *(const F3*)(w1zb + (unsigned)(ca).w + ln12); \
  p##4 = *(const F3*)(w1zb + (unsigned)(cb).x + ln12); \
  p##5 = *(const F3*)(w1zb + (unsigned)(cb).y + ln12); \
  p##6 = *(const F3*)(w1zb + (unsigned)(cb).z + ln12); \
  p##7 = *(const F3*)(w1zb + (unsigned)(cb).w + ln12); } while (0)

#define CONS8V3(p) do { \
  a1x += ((((p##0).x + (p##1).x) + ((p##2).x + (p##3).x)) + \
          (((p##4).x + (p##5).x) + ((p##6).x + (p##7).x))); \
  a1y += ((((p##0).y + (p##1).y) + ((p##2).y + (p##3).y)) + \
          (((p##4).y + (p##5).y) + ((p##6).y + (p##7).y))); \
  a1z += ((((p##0).z + (p##1).z) + ((p##2).z + (p##3).z)) + \
          (((p##4).z + (p##5).z) + ((p##6).z + (p##7).z))); \
} while (0)

// 2-deep software-pipelined gather over one spike-list segment (8 b32/group)
#define GATHER_SEG(nval, pA, pB, lbexpr) do { \
  const int ng_ = ((nval) + 7) >> 3; \
  if (ng_ > 0) { \
    const char* lb_ = (lbexpr); \
    float hA0,hA1,hA2,hA3,hA4,hA5,hA6,hA7; \
    float hB0,hB1,hB2,hB3,hB4,hB5,hB6,hB7; \
    int4 c1a, c1b, c2a, c2b; \
    ISS8L0(hA, pA, pB); \
    READC(c1a, c1b, lb_, 1); \
    READC(c2a, c2b, lb_, 2); \
    int g_ = 1; \
    _Pragma("unroll 1") \
    for (; g_ + 1 < ng_; g_ += 2) { \
      ISS8L0(hB, c1a, c1b); \
      READC(c1a, c1b, lb_, g_ + 2); \
      CONS8F(a0, hA); \
      ISS8L0(hA, c2a, c2b); \
      READC(c2a, c2b, lb_, g_ + 3); \
      CONS8F(a0, hB); \
    } \
    if (g_ < ng_) { ISS8L0(hB, c1a, c1b); CONS8F(a0, hA); CONS8F(a0, hB); } \
    else { CONS8F(a0, hA); } \
  } \
} while (0)

// 4 waves per batch. Waves 0-2: L0 slice of 64 neurons (1/lane, single ballot).
// Wave 3: all of L1 (3 neurons/lane, float3 global gather in flight across the
// whole step). One __syncthreads per timestep; double-buffered list0/counts/s0.
__global__ __launch_bounds__(256, 1) void snn_main_k(
    const float* __restrict__ x, const float* __restrict__ W_in,
    const float* __restrict__ b_in, const float* __restrict__ b_cells,
    const float* __restrict__ W_head, const float* __restrict__ b_head,
    const float* __restrict__ ws, float* __restrict__ out)
{
  extern __shared__ char lds[];
  const int tid = threadIdx.x;
  const int ln  = tid & 63;
  const int wv  = tid >> 6;          // 0..3
  const bool isW0 = (wv < 3);
  const int b   = blockIdx.x;
  const char* ldsb = lds;
  char* list1b = lds + LDS_LIST1;
  float* feat  = (float*)(lds + LDS_FEAT);
  const char* w1zb = (const char*)ws + 192 * ROWB;   // zero row = L1 offset base
  const unsigned nn4  = (unsigned)tid << 2;          // L0: neuron = tid (wv<3)
  const unsigned ln12 = (unsigned)ln * 12;

  // stage W0 (9216 float4) + zero everything above it
  {
    const float4* src = (const float4*)ws;
    float4* dst = (float4*)lds;
    for (int i = tid; i < (192 * ROWB) / 16; i += 256) dst[i] = src[i];
    float4 z4 = make_float4(0.f, 0.f, 0.f, 0.f);
    float4* zr = (float4*)(lds + L0_PAD);
    for (int i = tid; i < (LDS_TOTAL - L0_PAD) / 16; i += 256) zr[i] = z4;
  }
  __syncthreads();

  // ---- L0 per-lane constants (neuron nn = tid, valid for wv<3) ----
  const int nnc = isW0 ? tid : 0;
  const float wi0 = W_in[nnc * 3 + 0];
  const float wi1 = W_in[nnc * 3 + 1];
  const float wi2 = W_in[nnc * 3 + 2];
  const float zb  = b_in[nnc] + b_cells[nnc];
  // ---- wave3 per-lane constants (neurons 3ln..3ln+2) ----
  const float b1z0 = b_cells[HN + 3 * ln + 0];
  const float b1z1 = b_cells[HN + 3 * ln + 1];
  const float b1z2 = b_cells[HN + 3 * ln + 2];
  const int vo10 = (3 * ln + 1) * ROWB;
  const int vo11 = (3 * ln + 2) * ROWB;
  const int vo12 = (3 * ln + 3) * ROWB;

  const float* __restrict__ xb = x + (size_t)b * TT * 3;

  // persistent state
  float v0 = 0.0f;                                   // L0 (waves 0-2)
  float v10 = 0.f, v11 = 0.f, v12 = 0.f;             // L1 (wave 3)
  float cnt0 = 0.f, cnt1 = 0.f, cnt2 = 0.f;
  int ngl = 0;
  F3 gA0,gA1,gA2,gA3,gA4,gA5,gA6,gA7;
  F3 gB0,gB1,gB2,gB3,gB4,gB5,gB6,gB7;
  F3 gC0,gC1,gC2,gC3,gC4,gC5,gC6,gC7;
  F3 gD0,gD1,gD2,gD3,gD4,gD5,gD6,gD7;
  // L0 prefetch state
  int4 cntv = {0, 0, 0, 0};
  int4 p0a = {0,0,0,0}, p0b = {0,0,0,0}, p1a = {0,0,0,0},
       p1b = {0,0,0,0}, p2a = {0,0,0,0}, p2b = {0,0,0,0};
  const char* l0r = lds + LDS_LIST0 + 864;           // parity-1 (zeroed) for t=0
  float x0 = xb[0], x1 = xb[1], x2 = xb[2];

  #pragma unroll 1
  for (int t = 0; t < TT; ++t) {
    const int wp = t & 1;                            // write parity this step

    if (isW0) {
      // ================= Phase A: layer-0 slice =================
      const float z = x0 * wi0 + x1 * wi1 + x2 * wi2 + zb;
      float a0 = 0.f;
      const int ns0 = __builtin_amdgcn_readfirstlane(cntv.x);
      const int ns1 = __builtin_amdgcn_readfirstlane(cntv.y);
      const int ns2 = __builtin_amdgcn_readfirstlane(cntv.z);
      GATHER_SEG(ns0, p0a, p0b, l0r);
      GATHER_SEG(ns1, p1a, p1b, l0r + SEGB);
      GATHER_SEG(ns2, p2a, p2b, l0r + 2 * SEGB);

      const float aa = z + a0;
      v0 = v0 + (aa - v0) * 0.5f;                    // LIF charge (exact)
      const bool s = (v0 >= 1.0f);
      const unsigned long long m = __ballot(s ? 1 : 0);
      if (s) v0 = 0.0f;
      // publish s0(t)
      *(float*)(lds + LDS_S0 + wp * 768 + nn4) = s ? 1.0f : 0.0f;
      // compact segment list for step t+1
      char* l0w = lds + LDS_LIST0 + wp * 864 + wv * SEGB;
      if (s) *(int*)(l0w + 4 * lanecnt_lt(m)) = tid * ROWB;
      const int pc = (int)__popcll(m);
      if (ln < 8) *(int*)(l0w + 4 * (pc + ln)) = L0_PAD;
      if (ln == 0) *(int*)(lds + LDS_CNT + wp * 16 + wv * 4) = pc;
    }

    __syncthreads();   // s0/list0/counts(t) published

    if (isW0) {
      // ============ prefetch for Phase A(t+1) ============
      l0r = lds + LDS_LIST0 + wp * 864;
      cntv = *(const int4*)(lds + LDS_CNT + wp * 16);
      READC(p0a, p0b, l0r, 0);
      READC(p1a, p1b, l0r + SEGB, 0);
      READC(p2a, p2b, l0r + 2 * SEGB, 0);
      const int tn = (t + 1 < TT) ? t + 1 : 0;
      x0 = xb[tn * 3 + 0]; x1 = xb[tn * 3 + 1]; x2 = xb[tn * 3 + 2];
    } else {
      // ================= wave 3: layer 1 =================
      const char* s0r = lds + LDS_S0 + wp * 768;
      const float s0x = *(const float*)(s0r + ln12 + 0);
      const float s0y = *(const float*)(s0r + ln12 + 4);
      const float s0z = *(const float*)(s0r + ln12 + 8);
      // consume W1 gather issued last step (full step of flight time)
      float a1x = 0.f, a1y = 0.f, a1z = 0.f;
      if (ngl > 0) CONS8V3(gA);
      if (ngl > 1) CONS8V3(gB);
      if (ngl > 2) CONS8V3(gC);
      if (ngl > 3) CONS8V3(gD);
      if (ngl > 4) {                                  // overflow (>32 spikes)
        #pragma unroll 1
        for (int og = 4; og < ngl; ++og) {
          int4 ea, eb;
          READC(ea, eb, list1b, og);
          F3 r0,r1,r2,r3,r4,r5,r6,r7;
          ISS8W1(r, ea, eb);
          a1x += (((r0.x+r1.x)+(r2.x+r3.x))+((r4.x+r5.x)+(r6.x+r7.x)));
          a1y += (((r0.y+r1.y)+(r2.y+r3.y))+((r4.y+r5.y)+(r6.y+r7.y)));
          a1z += (((r0.z+r1.z)+(r2.z+r3.z))+((r4.z+r5.z)+(r6.z+r7.z)));
        }
      }
      // LIF layer 1 (neurons 3ln+k), compact own list
      int p = 0;
      {
        const float a1 = b1z0 + (a1x + s0x);
        v10 = v10 + (a1 - v10) * 0.5f;
        const bool s = (v10 >= 1.0f);
        const unsigned long long m = __ballot(s ? 1 : 0);
        if (s) { v10 = 0.0f; cnt0 += 1.0f;
                 *(int*)(list1b + 4 * (p + lanecnt_lt(m))) = vo10; }
        p += (int)__popcll(m);
      }
      {
        const float a1 = b1z1 + (a1y + s0y);
        v11 = v11 + (a1 - v11) * 0.5f;
        const bool s = (v11 >= 1.0f);
        const unsigned long long m = __ballot(s ? 1 : 0);
        if (s) { v11 = 0.0f; cnt1 += 1.0f;
                 *(int*)(list1b + 4 * (p + lanecnt_lt(m))) = vo11; }
        p += (int)__popcll(m);
      }
      {
        const float a1 = b1z2 + (a1z + s0z);
        v12 = v12 + (a1 - v12) * 0.5f;
        const bool s = (v12 >= 1.0f);
        const unsigned long long m = __ballot(s ? 1 : 0);
        if (s) { v12 = 0.0f; cnt2 += 1.0f;
                 *(int*)(list1b + 4 * (p + lanecnt_lt(m))) = vo12; }
        p += (int)__popcll(m);
      }
      if (ln < 8) *(int*)(list1b + 4 * (p + ln)) = 0;  // pads -> zero row
      const int ng1 = (p + 7) >> 3;
      int4 d0a,d0b,d1a,d1b,d2a,d2b,d3a,d3b;
      READC(d0a, d0b, list1b, 0);
      READC(d1a, d1b, list1b, 1);
      READC(d2a, d2b, list1b, 2);
      READC(d3a, d3b, list1b, 3);
      if (ng1 > 0) ISS8W1(gA, d0a, d0b);               // fly across next step
      if (ng1 > 1) ISS8W1(gB, d1a, d1b);
      if (ng1 > 2) ISS8W1(gC, d2a, d2b);
      if (ng1 > 3) ISS8W1(gD, d3a, d3b);
      ngl = ng1;
    }
  }

  // ---- epilogue: exact mean (count * 2^-11) + head GEMV ----
  if (wv == 3) {
    const float r = 1.0f / 2048.0f;
    *(float*)((char*)feat + ln12 + 0) = cnt0 * r;
    *(float*)((char*)feat + ln12 + 4) = cnt1 * r;
    *(float*)((char*)feat + ln12 + 8) = cnt2 * r;
  }
  __syncthreads();
  if (tid < NCLS) {
    float a = b_head[tid];
    const float* wh = W_head + tid * HN;
    #pragma unroll 8
    for (int q = 0; q < HN; ++q) a += feat[q] * wh[q];
    out[b * NCLS + tid] = a;
  }
}

extern "C" void kernel_launch(void* const* d_in, const int* in_sizes, int n_in,
                              void* d_out, int out_size, void* d_ws, size_t ws_size,
                              hipStream_t stream) {
  const float* x       = (const float*)d_in[0];
  const float* W_in    = (const float*)d_in[1];
  const float* b_in    = (const float*)d_in[2];
  const float* W_cells = (const float*)d_in[3];
  const float* b_cells = (const float*)d_in[4];
  const float* W_head  = (const float*)d_in[5];
  const float* b_head  = (const float*)d_in[6];
  float* out = (float*)d_out;
  float* ws  = (float*)d_ws;   // 296704 bytes used

  snn_pack_k<<<(2 * HN * HN + 512 + 255) / 256, 256, 0, stream>>>(W_cells, ws);
  snn_main_k<<<128, 256, LDS_TOTAL, stream>>>(
      x, W_in, b_in, b_cells, W_head, b_head, ws, out);
}